// Round 1
// baseline (223.599 us; speedup 1.0000x reference)
//
#include <hip/hip_runtime.h>

typedef __attribute__((ext_vector_type(8))) unsigned short ushort8;
typedef __attribute__((ext_vector_type(8))) short short8;
typedef __attribute__((ext_vector_type(4))) float f32x4;

#define M_DIM 8192
#define N_DIM 2048
#define K_DIM 2048
#define BM 128
#define BN 128
#define BK 32

// ---- fp32 -> bf16 (RNE) cast, 8 elems/thread, 16B stores ----
__device__ __forceinline__ unsigned short f32_to_bf16(float f) {
  unsigned int u = __float_as_uint(f);
  u += 0x7fffu + ((u >> 16) & 1u);   // round-to-nearest-even
  return (unsigned short)(u >> 16);
}

__global__ void __launch_bounds__(256) cast_f32_bf16_x8(
    const float* __restrict__ src, unsigned short* __restrict__ dst, int n) {
  int i = (blockIdx.x * 256 + threadIdx.x) * 8;
  if (i + 8 > n) return;
  float4 a = *(const float4*)(src + i);
  float4 b = *(const float4*)(src + i + 4);
  ushort8 r;
  r[0] = f32_to_bf16(a.x); r[1] = f32_to_bf16(a.y);
  r[2] = f32_to_bf16(a.z); r[3] = f32_to_bf16(a.w);
  r[4] = f32_to_bf16(b.x); r[5] = f32_to_bf16(b.y);
  r[6] = f32_to_bf16(b.z); r[7] = f32_to_bf16(b.w);
  *(ushort8*)(dst + i) = r;
}

// ---- async global->LDS, 16B per lane (wave-uniform base + lane*16) ----
__device__ __forceinline__ void gload_lds16(const unsigned short* g, unsigned short* l) {
  __builtin_amdgcn_global_load_lds(
      (const __attribute__((address_space(1))) void*)g,
      (__attribute__((address_space(3))) void*)l,
      16, 0, 0);
}

// ---- m97-style bf16 GEMM, C = A(MxK) * B(NxK)^T + bias, fp32 out ----
// block = 256 threads (4 waves), 128x128 tile, BK=32, 16x16x32 bf16 MFMA.
__global__ void __launch_bounds__(256) gemm_bt_bias(
    const unsigned short* __restrict__ A,   // M x K bf16
    const unsigned short* __restrict__ B,   // N x K bf16
    const float* __restrict__ bias,         // N fp32
    float* __restrict__ C) {                // M x N fp32
  __shared__ unsigned short sA[BM * BK];    // 8 KB, row-major (row stride BK)
  __shared__ unsigned short sB[BN * BK];    // 8 KB

  const int tid  = threadIdx.x;
  const int lane = tid & 63;
  const int wave = tid >> 6;
  const int wm = wave & 1;                  // wave m offset (x64)
  const int wn = wave >> 1;                 // wave n offset (x64)
  const int bm0 = blockIdx.y * BM;
  const int bn0 = blockIdx.x * BN;

  // staging: 512 chunks of 16B per tile; thread handles chunks tid, tid+256.
  // chunk c -> row c/4, col (c%4)*8 ; LDS offset c*16 B (row-major, matches
  // the wave-uniform-base + lane*16 hardware layout since c == tid).
  const int c0 = tid,       r0 = c0 >> 2, cc0 = (c0 & 3) * 8;
  const int c1 = tid + 256, r1 = c1 >> 2, cc1 = (c1 & 3) * 8;

  const unsigned short* Ag0 = A + (size_t)(bm0 + r0) * K_DIM + cc0;
  const unsigned short* Ag1 = A + (size_t)(bm0 + r1) * K_DIM + cc1;
  const unsigned short* Bg0 = B + (size_t)(bn0 + r0) * K_DIM + cc0;
  const unsigned short* Bg1 = B + (size_t)(bn0 + r1) * K_DIM + cc1;

  unsigned short* sA0 = sA + c0 * 8;
  unsigned short* sA1 = sA + c1 * 8;
  unsigned short* sB0 = sB + c0 * 8;
  unsigned short* sB1 = sB + c1 * 8;

  // MFMA fragment coords: A[m=lane&15][k=(lane>>4)*8 + j]
  const int frow = lane & 15;
  const int fk   = (lane >> 4) * 8;

  f32x4 acc[4][4] = {};

  for (int k0 = 0; k0 < K_DIM; k0 += BK) {
    gload_lds16(Ag0 + k0, sA0);
    gload_lds16(Ag1 + k0, sA1);
    gload_lds16(Bg0 + k0, sB0);
    gload_lds16(Bg1 + k0, sB1);
    __syncthreads();   // drains vmcnt -> LDS tiles valid

    short8 af[4], bf[4];
#pragma unroll
    for (int mi = 0; mi < 4; ++mi) {
      int row = wm * 64 + mi * 16 + frow;
      af[mi] = *(const short8*)(sA + row * BK + fk);
    }
#pragma unroll
    for (int ni = 0; ni < 4; ++ni) {
      int row = wn * 64 + ni * 16 + frow;
      bf[ni] = *(const short8*)(sB + row * BK + fk);
    }
#pragma unroll
    for (int mi = 0; mi < 4; ++mi)
#pragma unroll
      for (int ni = 0; ni < 4; ++ni)
        acc[mi][ni] = __builtin_amdgcn_mfma_f32_16x16x32_bf16(
            af[mi], bf[ni], acc[mi][ni], 0, 0, 0);
    __syncthreads();   // protect LDS from next iteration's staging
  }

  // epilogue: C/D layout col=lane&15, row=(lane>>4)*4+reg
  const int col16 = lane & 15;
  const int row4  = (lane >> 4) * 4;
#pragma unroll
  for (int ni = 0; ni < 4; ++ni) {
    int gcol = bn0 + wn * 64 + ni * 16 + col16;
    float bv = bias[gcol];
#pragma unroll
    for (int mi = 0; mi < 4; ++mi) {
      int grow = bm0 + wm * 64 + mi * 16 + row4;
#pragma unroll
      for (int r = 0; r < 4; ++r) {
        C[(size_t)(grow + r) * N_DIM + gcol] = acc[mi][ni][r] + bv;
      }
    }
  }
}

extern "C" void kernel_launch(void* const* d_in, const int* in_sizes, int n_in,
                              void* d_out, int out_size, void* d_ws, size_t ws_size,
                              hipStream_t stream) {
  const float* x = (const float*)d_in[0];   // 4*2048*2048
  const float* W = (const float*)d_in[1];   // 2048*2048
  const float* b = (const float*)d_in[2];   // 2048
  float* out = (float*)d_out;               // 8192*2048 fp32

  unsigned short* xb = (unsigned short*)d_ws;            // 33.5 MB
  unsigned short* Wb = xb + (size_t)M_DIM * K_DIM;       // + 8.4 MB (ws >= 42 MB)

  const int nx = M_DIM * K_DIM;  // 16777216
  const int nw = N_DIM * K_DIM;  // 4194304
  cast_f32_bf16_x8<<<nx / (256 * 8), 256, 0, stream>>>(x, xb, nx);
  cast_f32_bf16_x8<<<nw / (256 * 8), 256, 0, stream>>>(W, Wb, nw);

  dim3 grid(N_DIM / BN, M_DIM / BM);  // (16, 64) = 1024 blocks
  gemm_bt_bias<<<grid, 256, 0, stream>>>(xb, Wb, b, out);
}

// Round 2
// 198.339 us; speedup vs baseline: 1.1274x; 1.1274x over previous
//
#include <hip/hip_runtime.h>

typedef __attribute__((ext_vector_type(8))) unsigned short ushort8;
typedef __attribute__((ext_vector_type(8))) short short8;
typedef __attribute__((ext_vector_type(4))) float f32x4;

#define M_DIM 8192
#define N_DIM 2048
#define K_DIM 2048
#define BM 128
#define BN 128
#define BK 64   // 8 chunks of 8 bf16 per row -> 3-bit XOR swizzle kills bank conflicts

// ---- fp32 -> bf16 (RNE) ----
__device__ __forceinline__ unsigned short f32_to_bf16(float f) {
  unsigned int u = __float_as_uint(f);
  u += 0x7fffu + ((u >> 16) & 1u);
  return (unsigned short)(u >> 16);
}

// one kernel casts both x and W (saves a launch gap)
__global__ void __launch_bounds__(256) cast_both_x8(
    const float* __restrict__ x, const float* __restrict__ W,
    unsigned short* __restrict__ xb, unsigned short* __restrict__ Wb) {
  const long nx = (long)M_DIM * K_DIM;
  long i = ((long)blockIdx.x * 256 + threadIdx.x) * 8;
  const float* s;
  unsigned short* d;
  if (i < nx) { s = x + i; d = xb + i; }
  else        { s = W + (i - nx); d = Wb + (i - nx); }
  float4 a = *(const float4*)(s);
  float4 b = *(const float4*)(s + 4);
  ushort8 r;
  r[0] = f32_to_bf16(a.x); r[1] = f32_to_bf16(a.y);
  r[2] = f32_to_bf16(a.z); r[3] = f32_to_bf16(a.w);
  r[4] = f32_to_bf16(b.x); r[5] = f32_to_bf16(b.y);
  r[6] = f32_to_bf16(b.z); r[7] = f32_to_bf16(b.w);
  *(ushort8*)(d) = r;
}

__device__ __forceinline__ void gload_lds16(const unsigned short* g, unsigned short* l) {
  __builtin_amdgcn_global_load_lds(
      (const __attribute__((address_space(1))) void*)g,
      (__attribute__((address_space(3))) void*)l,
      16, 0, 0);
}

// C = A(MxK) * B(NxK)^T + bias. 128x128 tile, BK=64, XOR-swizzled LDS.
// LDS image: chunk p (16B) at offset p*16; chunk p holds global k-chunk
// (p&7)^(row&7) of row p>>3. Fragment reads then hit all 8 bank groups.
__global__ void __launch_bounds__(256) gemm_bt_bias(
    const unsigned short* __restrict__ A,
    const unsigned short* __restrict__ B,
    const float* __restrict__ bias,
    float* __restrict__ C) {
  __shared__ unsigned short sA[BM * BK];  // 16 KB
  __shared__ unsigned short sB[BN * BK];  // 16 KB

  const int tid  = threadIdx.x;
  const int lane = tid & 63;
  const int wave = tid >> 6;
  const int wm = wave & 1;
  const int wn = wave >> 1;
  const int bm0 = blockIdx.y * BM;
  const int bn0 = blockIdx.x * BN;

  // staging: 1024 chunks of 16B per matrix; thread handles p = tid + 256*j
  const unsigned short* Ag[4];
  const unsigned short* Bg[4];
  unsigned short* sAd[4];
  unsigned short* sBd[4];
#pragma unroll
  for (int j = 0; j < 4; ++j) {
    int p = tid + 256 * j;
    int r = p >> 3;
    int cbg = (p & 7) ^ (r & 7);          // global k-chunk this slot holds
    Ag[j] = A + (size_t)(bm0 + r) * K_DIM + cbg * 8;
    Bg[j] = B + (size_t)(bn0 + r) * K_DIM + cbg * 8;
    sAd[j] = sA + p * 8;
    sBd[j] = sB + p * 8;
  }

  // fragment LDS element-offsets (loop-invariant):
  // A[m=lane&15][k=(lane>>4)*8+j], substep s adds 32 to k
  const int frow = lane & 15;
  const int q    = lane >> 4;
  int aoff[4][2], boff[4][2];
#pragma unroll
  for (int mi = 0; mi < 4; ++mi) {
    int rr = wm * 64 + mi * 16 + frow;
    int rb = rr & 7;
#pragma unroll
    for (int s = 0; s < 2; ++s) {
      int cb = s * 4 + q;
      aoff[mi][s] = (rr * 8 + (cb ^ rb)) * 8;
    }
  }
#pragma unroll
  for (int ni = 0; ni < 4; ++ni) {
    int rr = wn * 64 + ni * 16 + frow;
    int rb = rr & 7;
#pragma unroll
    for (int s = 0; s < 2; ++s) {
      int cb = s * 4 + q;
      boff[ni][s] = (rr * 8 + (cb ^ rb)) * 8;
    }
  }

  f32x4 acc[4][4] = {};

  for (int k0 = 0; k0 < K_DIM; k0 += BK) {
#pragma unroll
    for (int j = 0; j < 4; ++j) {
      gload_lds16(Ag[j] + k0, sAd[j]);
      gload_lds16(Bg[j] + k0, sBd[j]);
    }
    __syncthreads();

#pragma unroll
    for (int s = 0; s < 2; ++s) {
      short8 af[4], bf[4];
#pragma unroll
      for (int mi = 0; mi < 4; ++mi) af[mi] = *(const short8*)(sA + aoff[mi][s]);
#pragma unroll
      for (int ni = 0; ni < 4; ++ni) bf[ni] = *(const short8*)(sB + boff[ni][s]);
#pragma unroll
      for (int mi = 0; mi < 4; ++mi)
#pragma unroll
        for (int ni = 0; ni < 4; ++ni)
          acc[mi][ni] = __builtin_amdgcn_mfma_f32_16x16x32_bf16(
              af[mi], bf[ni], acc[mi][ni], 0, 0, 0);
    }
    __syncthreads();
  }

  // epilogue: C/D layout col=lane&15, row=(lane>>4)*4+reg
  const int col16 = lane & 15;
  const int row4  = (lane >> 4) * 4;
#pragma unroll
  for (int ni = 0; ni < 4; ++ni) {
    int gcol = bn0 + wn * 64 + ni * 16 + col16;
    float bv = bias[gcol];
#pragma unroll
    for (int mi = 0; mi < 4; ++mi) {
      int grow = bm0 + wm * 64 + mi * 16 + row4;
#pragma unroll
      for (int r = 0; r < 4; ++r) {
        C[(size_t)(grow + r) * N_DIM + gcol] = acc[mi][ni][r] + bv;
      }
    }
  }
}

extern "C" void kernel_launch(void* const* d_in, const int* in_sizes, int n_in,
                              void* d_out, int out_size, void* d_ws, size_t ws_size,
                              hipStream_t stream) {
  const float* x = (const float*)d_in[0];
  const float* W = (const float*)d_in[1];
  const float* b = (const float*)d_in[2];
  float* out = (float*)d_out;

  unsigned short* xb = (unsigned short*)d_ws;
  unsigned short* Wb = xb + (size_t)M_DIM * K_DIM;

  const long ntot = (long)M_DIM * K_DIM + (long)N_DIM * K_DIM;  // 20971520
  cast_both_x8<<<(int)(ntot / (256 * 8)), 256, 0, stream>>>(x, W, xb, Wb);

  dim3 grid(N_DIM / BN, M_DIM / BM);  // (16, 64)
  gemm_bt_bias<<<grid, 256, 0, stream>>>(xb, Wb, b, out);
}

// Round 3
// 197.088 us; speedup vs baseline: 1.1345x; 1.0063x over previous
//
#include <hip/hip_runtime.h>

typedef __attribute__((ext_vector_type(8))) unsigned short ushort8;
typedef __attribute__((ext_vector_type(8))) short short8;
typedef __attribute__((ext_vector_type(16))) float f32x16;

#define M_DIM 8192
#define N_DIM 2048
#define K_DIM 2048
#define BM 128
#define BN 128
#define BK 64

// ---- fp32 -> bf16 (RNE) ----
__device__ __forceinline__ unsigned short f32_to_bf16(float f) {
  unsigned int u = __float_as_uint(f);
  u += 0x7fffu + ((u >> 16) & 1u);
  return (unsigned short)(u >> 16);
}

__global__ void __launch_bounds__(256) cast_both_x8(
    const float* __restrict__ x, const float* __restrict__ W,
    unsigned short* __restrict__ xb, unsigned short* __restrict__ Wb) {
  const long nx = (long)M_DIM * K_DIM;
  long i = ((long)blockIdx.x * 256 + threadIdx.x) * 8;
  const float* s;
  unsigned short* d;
  if (i < nx) { s = x + i; d = xb + i; }
  else        { s = W + (i - nx); d = Wb + (i - nx); }
  float4 a = *(const float4*)(s);
  float4 b = *(const float4*)(s + 4);
  ushort8 r;
  r[0] = f32_to_bf16(a.x); r[1] = f32_to_bf16(a.y);
  r[2] = f32_to_bf16(a.z); r[3] = f32_to_bf16(a.w);
  r[4] = f32_to_bf16(b.x); r[5] = f32_to_bf16(b.y);
  r[6] = f32_to_bf16(b.z); r[7] = f32_to_bf16(b.w);
  *(ushort8*)(d) = r;
}

__device__ __forceinline__ void gload_lds16(const unsigned short* g, unsigned short* l) {
  __builtin_amdgcn_global_load_lds(
      (const __attribute__((address_space(1))) void*)g,
      (__attribute__((address_space(3))) void*)l,
      16, 0, 0);
}

// C = A(MxK) * B(NxK)^T + bias. 128x128 tile, BK=64, XOR-swizzled LDS,
// 32x32x16 bf16 MFMA (2x2 tiles of 32x32 per wave).
// LDS image: chunk p (16B) at offset p*16; chunk p holds global k-chunk
// (p&7)^(row&7) of row p>>3.
__global__ void __launch_bounds__(256) gemm_bt_bias(
    const unsigned short* __restrict__ A,
    const unsigned short* __restrict__ B,
    const float* __restrict__ bias,
    float* __restrict__ C) {
  __shared__ unsigned short sA[BM * BK];  // 16 KB
  __shared__ unsigned short sB[BN * BK];  // 16 KB

  const int tid  = threadIdx.x;
  const int lane = tid & 63;
  const int wave = tid >> 6;
  const int wm = wave & 1;
  const int wn = wave >> 1;

  // grid: 1D, column-major tile order -> 8 co-resident blocks per XCD share
  // one B panel (0.5 MB) + 8 A panels (4 MB) ~ per-XCD L2
  const int L = blockIdx.x;
  const int bm0 = (L & 63) * BM;
  const int bn0 = (L >> 6) * BN;

  // staging: 1024 chunks of 16B per matrix; thread handles p = tid + 256*j
  const unsigned short* Ag[4];
  const unsigned short* Bg[4];
  unsigned short* sAd[4];
  unsigned short* sBd[4];
#pragma unroll
  for (int j = 0; j < 4; ++j) {
    int p = tid + 256 * j;
    int r = p >> 3;
    int cbg = (p & 7) ^ (r & 7);
    Ag[j] = A + (size_t)(bm0 + r) * K_DIM + cbg * 8;
    Bg[j] = B + (size_t)(bn0 + r) * K_DIM + cbg * 8;
    sAd[j] = sA + p * 8;
    sBd[j] = sB + p * 8;
  }

  // 32x32x16 fragment coords: A[m=lane&31][k=(lane>>5)*8+j]
  const int frow = lane & 31;
  const int half = lane >> 5;
  int aoff[2][4], boff[2][4];
#pragma unroll
  for (int mi = 0; mi < 2; ++mi) {
    int rr = wm * 64 + mi * 32 + frow;
    int rb = rr & 7;
#pragma unroll
    for (int s = 0; s < 4; ++s) {
      int cb = s * 2 + half;
      aoff[mi][s] = (rr * 8 + (cb ^ rb)) * 8;
    }
  }
#pragma unroll
  for (int ni = 0; ni < 2; ++ni) {
    int rr = wn * 64 + ni * 32 + frow;
    int rb = rr & 7;
#pragma unroll
    for (int s = 0; s < 4; ++s) {
      int cb = s * 2 + half;
      boff[ni][s] = (rr * 8 + (cb ^ rb)) * 8;
    }
  }

  f32x16 acc[2][2] = {};

  for (int k0 = 0; k0 < K_DIM; k0 += BK) {
#pragma unroll
    for (int j = 0; j < 4; ++j) {
      gload_lds16(Ag[j] + k0, sAd[j]);
      gload_lds16(Bg[j] + k0, sBd[j]);
    }
    __syncthreads();

#pragma unroll
    for (int s = 0; s < 4; ++s) {
      short8 af[2], bf[2];
#pragma unroll
      for (int mi = 0; mi < 2; ++mi) af[mi] = *(const short8*)(sA + aoff[mi][s]);
#pragma unroll
      for (int ni = 0; ni < 2; ++ni) bf[ni] = *(const short8*)(sB + boff[ni][s]);
#pragma unroll
      for (int mi = 0; mi < 2; ++mi)
#pragma unroll
        for (int ni = 0; ni < 2; ++ni)
          acc[mi][ni] = __builtin_amdgcn_mfma_f32_32x32x16_bf16(
              af[mi], bf[ni], acc[mi][ni], 0, 0, 0);
    }
    __syncthreads();
  }

  // epilogue: 32x32 C/D layout col=lane&31, row=(r&3)+8*(r>>2)+4*(lane>>5)
#pragma unroll
  for (int ni = 0; ni < 2; ++ni) {
    int gcol = bn0 + wn * 64 + ni * 32 + frow;
    float bv = bias[gcol];
#pragma unroll
    for (int mi = 0; mi < 2; ++mi) {
      int rbase = bm0 + wm * 64 + mi * 32 + 4 * half;
#pragma unroll
      for (int r = 0; r < 16; ++r) {
        int grow = rbase + (r & 3) + 8 * (r >> 2);
        C[(size_t)grow * N_DIM + gcol] = acc[mi][ni][r] + bv;
      }
    }
  }
}

extern "C" void kernel_launch(void* const* d_in, const int* in_sizes, int n_in,
                              void* d_out, int out_size, void* d_ws, size_t ws_size,
                              hipStream_t stream) {
  const float* x = (const float*)d_in[0];
  const float* W = (const float*)d_in[1];
  const float* b = (const float*)d_in[2];
  float* out = (float*)d_out;

  unsigned short* xb = (unsigned short*)d_ws;
  unsigned short* Wb = xb + (size_t)M_DIM * K_DIM;

  const long ntot = (long)M_DIM * K_DIM + (long)N_DIM * K_DIM;
  cast_both_x8<<<(int)(ntot / (256 * 8)), 256, 0, stream>>>(x, W, xb, Wb);

  gemm_bt_bias<<<(M_DIM / BM) * (N_DIM / BN), 256, 0, stream>>>(xb, Wb, b, out);
}